// Round 1
// baseline (816.852 us; speedup 1.0000x reference)
//
#include <hip/hip_runtime.h>
#include <stddef.h>

#define TT 2048
#define NN 4096
#define LSEG 64
#define NSEG (TT / LSEG)   // 32
#define TPB 256
#define TPA 1024           // phase A: single block, 1024 threads
#define NPT 4              // neurons per thread (TPA * NPT == NN)
#define NOFIRE 0xFFFFFFFEu

// ---------------- Phase A: exact coupled simulation, SINGLE WORKGROUP ----------------
// 1 block x 1024 threads, 4 neurons per thread, all state in registers.
// Per coupled step the only global quantity is the min firing index:
//   per-thread min over 4 -> wave shfl min -> 16 lane-0s publish to LDS ->
//   one __syncthreads -> every thread min-reduces the 16 LDS words (broadcast reads).
// LDS slot array is double-buffered by step parity so ONE barrier per step suffices
// (step t+2's write to buffer t&1 is fenced from step t's readers by the t+1 barrier).
// No cross-block traffic, no slots protocol, no memset.
__global__ __launch_bounds__(TPA) void phaseA(
    const float* __restrict__ ts, const float* __restrict__ inp,
    const float* __restrict__ w, const float* __restrict__ v0,
    const float* __restrict__ i0, const float* __restrict__ mu,
    const float* __restrict__ s0u, const float* __restrict__ ru,
    const int* __restrict__ mx, float* __restrict__ ys,
    unsigned int* __restrict__ hdr)
{
#pragma clang fp contract(off)
  const int tid = threadIdx.x;
  const int wid = tid >> 6;
  const int lane = tid & 63;
  const float dt = ts[1] - ts[0];
  const float mu1 = mu[0], mu2 = mu[1];
  const int maxs = mx[0];

  const float4* inp4 = (const float4*)inp;
  const float4* ru4  = (const float4*)ru;
  const float4* w4   = (const float4*)w;

  float4 v4 = ((const float4*)v0)[tid];
  float4 i4 = ((const float4*)i0)[tid];
  float4 s04 = ((const float4*)s0u)[tid];

  float v[NPT]    = {v4.x, v4.y, v4.z, v4.w};
  float i_nw[NPT] = {i4.x, i4.y, i4.z, i4.w};  // i, possibly missing last step's w add
  float s[NPT];
  {
    float su[NPT] = {s04.x, s04.y, s04.z, s04.w};
#pragma unroll
    for (int k = 0; k < NPT; ++k) s[k] = logf(su[k] + 1e-12f) - 0.01f;
  }
  float wv[NPT] = {0.0f, 0.0f, 0.0f, 0.0f};
  bool  aw[NPT] = {false, false, false, false};
  float4 inpv = inp4[tid];   // row 0 prefetched
  float4 ruv  = ru4[tid];
  int nsp = 0;
  int t_stop = TT;

  __shared__ unsigned int shw[2][TPA / 64];   // double-buffered by step parity

  for (int t = 0; t < TT; ++t) {
    // prefetch next row (consumed next iteration; hides HBM latency behind compute)
    float4 inpv_n = make_float4(0.f, 0.f, 0.f, 0.f);
    float4 ruv_n  = make_float4(0.f, 0.f, 0.f, 0.f);
    if (t + 1 < TT) {
      inpv_n = inp4[(size_t)(t + 1) * (NN / 4) + tid];
      ruv_n  = ru4[(size_t)(t + 1) * (NN / 4) + tid];
    }
    float iv[NPT] = {inpv.x, inpv.y, inpv.z, inpv.w};
    float rv[NPT] = {ruv.x, ruv.y, ruv.z, ruv.w};

    float sn[NPT]; bool ev[NPT];
#pragma unroll
    for (int k = 0; k < NPT; ++k) {
      float sig = 1.0f / (1.0f + expf(-v[k]));
      sn[k] = s[k] + dt * sig;
      ev[k] = sn[k] >= 0.0f;
    }
    bool coupled = (nsp < maxs);   // uniform across block

    unsigned int gm = NOFIRE;
    if (coupled) {
      unsigned int m = NOFIRE;
#pragma unroll
      for (int k = 0; k < NPT; ++k) {
        unsigned int c = ev[k] ? (unsigned int)(tid * NPT + k) : NOFIRE;
        m = m < c ? m : c;
      }
#pragma unroll
      for (int off = 32; off > 0; off >>= 1) {
        unsigned int o = (unsigned int)__shfl_down((int)m, off, 64);
        m = m < o ? m : o;
      }
      if (lane == 0) shw[t & 1][wid] = m;
      __syncthreads();
      unsigned int bm = shw[t & 1][0];
#pragma unroll
      for (int b = 1; b < TPA / 64; ++b) {
        unsigned int x = shw[t & 1][b];
        bm = bm < x ? bm : x;
      }
      gm = bm;
    }

    // resolve last step's pending w-row add (load issued a full iteration ago)
    float ifull[NPT];
#pragma unroll
    for (int k = 0; k < NPT; ++k) ifull[k] = aw[k] ? (i_nw[k] + wv[k]) : i_nw[k];
    // deferred store of ys[t-1] (now that i is final); 48 contiguous bytes/thread
    if (t > 0) {
      size_t o = ((size_t)(t - 1) * NN + (size_t)tid * NPT) * 3;
      float4* yo = (float4*)(ys + o);
      yo[0] = make_float4(v[0], ifull[0], s[0], v[1]);
      yo[1] = make_float4(ifull[1], s[1], v[2], ifull[2]);
      yo[2] = make_float4(s[2], v[3], ifull[3], s[3]);
    }

    // step-t drift (numpy op order, no contraction)
    float vn[NPT], in_[NPT];
#pragma unroll
    for (int k = 0; k < NPT; ++k) {
      vn[k]  = v[k] + dt * (mu1 * (ifull[k] - v[k]) + mu1 * iv[k]);
      in_[k] = ifull[k] + dt * (-mu2 * ifull[k]);
    }

    bool fire = coupled && (gm < (unsigned int)NN);
#pragma unroll
    for (int k = 0; k < NPT; ++k) aw[k] = false;
    if (fire) {
      nsp += 1;
      // issue gather; wv regs are the load dests, first USE is next iteration,
      // so the vmcnt wait lands a full iteration later (latency hidden)
      float4 wr = w4[(size_t)gm * (NN / 4) + tid];
      wv[0] = wr.x; wv[1] = wr.y; wv[2] = wr.z; wv[3] = wr.w;
#pragma unroll
      for (int k = 0; k < NPT; ++k) {
        if (ev[k]) {
          v[k] = vn[k] - 1.0f;
          s[k] = logf(rv[k] + 1e-12f) - 0.01f;   // logf only under rare ev predicate
        } else {
          v[k] = vn[k]; s[k] = sn[k]; aw[k] = true;
        }
      }
    } else {
#pragma unroll
      for (int k = 0; k < NPT; ++k) { v[k] = vn[k]; s[k] = sn[k]; }
    }
#pragma unroll
    for (int k = 0; k < NPT; ++k) i_nw[k] = in_[k];
    inpv = inpv_n; ruv = ruv_n;

    if (nsp >= maxs && ((t + 1) & (LSEG - 1)) == 0) { t_stop = t + 1; break; }
  }

  // flush final deferred store
  {
    float ifull[NPT];
#pragma unroll
    for (int k = 0; k < NPT; ++k) ifull[k] = aw[k] ? (i_nw[k] + wv[k]) : i_nw[k];
    size_t o = ((size_t)(t_stop - 1) * NN + (size_t)tid * NPT) * 3;
    float4* yo = (float4*)(ys + o);
    yo[0] = make_float4(v[0], ifull[0], s[0], v[1]);
    yo[1] = make_float4(ifull[1], s[1], v[2], ifull[2]);
    yo[2] = make_float4(s[2], v[3], ifull[3], s[3]);
  }
  if (tid == 0) hdr[0] = (unsigned int)t_stop;
}

// ---------------- Phase B: decoupled closed-form tail (unchanged) ----------------
// P1: per (neuron, segment): C = sum_j a^(L-1-j) * b * (i_j + inp_j), i_j geometric.
__global__ __launch_bounds__(TPB) void p1_segc(
    const float* __restrict__ ts, const float* __restrict__ inp,
    const float* __restrict__ mu, const float* __restrict__ ys,
    const unsigned int* __restrict__ hdr, float* __restrict__ buf1)
{
  unsigned int Kp = hdr[0];
  unsigned int g0 = Kp / LSEG;
  unsigned int g = blockIdx.x >> 4;
  if (g < g0) return;
  int n = (blockIdx.x & 15) * TPB + threadIdx.x;
  float dt = ts[1] - ts[0];
  float mu1 = mu[0], mu2 = mu[1];
  float a = 1.0f - dt * mu1, b = dt * mu1, r = 1.0f - dt * mu2;
  float ibase = ys[((size_t)(Kp - 1) * NN + n) * 3 + 1];
  float ij = ibase * powf(r, (float)((int)(g * LSEG) - (int)Kp));
  float c = 0.0f;
  size_t base = (size_t)(g * LSEG) * NN + n;
  for (int j = 0; j < LSEG; ++j) {
    float x = inp[base + (size_t)j * NN];
    c = a * c + b * (ij + x);
    ij *= r;
  }
  buf1[(size_t)g * NN + n] = c;
}

// P2: per neuron, scan segment-boundary v:  v_{g+1} = a^L v_g + C_g (in place -> Vb)
__global__ __launch_bounds__(TPB) void p2_scanv(
    const float* __restrict__ ts, const float* __restrict__ mu,
    const float* __restrict__ ys, const unsigned int* __restrict__ hdr,
    float* __restrict__ buf1)
{
  unsigned int Kp = hdr[0];
  unsigned int g0 = Kp / LSEG;
  if (g0 >= NSEG) return;
  int n = blockIdx.x * TPB + threadIdx.x;
  float dt = ts[1] - ts[0];
  float mu1 = mu[0];
  float a = 1.0f - dt * mu1;
  float aL = a;
  for (int k = 0; k < 6; ++k) aL *= aL;   // a^64
  float v = ys[((size_t)(Kp - 1) * NN + n) * 3 + 0];
  for (unsigned int g = g0; g < NSEG; ++g) {
    float cg = buf1[(size_t)g * NN + n];
    buf1[(size_t)g * NN + n] = v;
    v = aL * v + cg;
  }
}

// P3: per (neuron, segment): replay 64 steps; write v,i and local s-prefix to ys;
// stash segment sigma-sum into buf2.
__global__ __launch_bounds__(TPB) void p3_seg(
    const float* __restrict__ ts, const float* __restrict__ inp,
    const float* __restrict__ mu, const unsigned int* __restrict__ hdr,
    const float* __restrict__ buf1, float* __restrict__ buf2,
    float* __restrict__ ys)
{
  unsigned int Kp = hdr[0];
  unsigned int g0 = Kp / LSEG;
  unsigned int g = blockIdx.x >> 4;
  if (g < g0) return;
  int n = (blockIdx.x & 15) * TPB + threadIdx.x;
  float dt = ts[1] - ts[0];
  float mu1 = mu[0], mu2 = mu[1];
  float r = 1.0f - dt * mu2;
  float v = buf1[(size_t)g * NN + n];
  float ibase = ys[((size_t)(Kp - 1) * NN + n) * 3 + 1];
  float i = ibase * powf(r, (float)((int)(g * LSEG) - (int)Kp));
  float sl = 0.0f;
  for (int j = 0; j < LSEG; ++j) {
    size_t t = (size_t)g * LSEG + j;
    float x = inp[t * NN + n];
    float sig = 1.0f / (1.0f + expf(-v));
    sl = sl + dt * sig;
    float vn  = v + dt * (mu1 * (i - v) + mu1 * x);
    float in_ = i + dt * (-mu2 * i);
    size_t o = (t * NN + n) * 3;
    ys[o] = vn; ys[o + 1] = in_; ys[o + 2] = sl;
    v = vn; i = in_;
  }
  buf2[(size_t)g * NN + n] = sl;
}

// P4: per neuron, scan sigma-sums -> s at segment starts (in place -> Sb)
__global__ __launch_bounds__(TPB) void p4_scans(
    const float* __restrict__ ys, const unsigned int* __restrict__ hdr,
    float* __restrict__ buf2)
{
  unsigned int Kp = hdr[0];
  unsigned int g0 = Kp / LSEG;
  if (g0 >= NSEG) return;
  int n = blockIdx.x * TPB + threadIdx.x;
  float s = ys[((size_t)(Kp - 1) * NN + n) * 3 + 2];
  for (unsigned int g = g0; g < NSEG; ++g) {
    float t = buf2[(size_t)g * NN + n];
    buf2[(size_t)g * NN + n] = s;
    s += t;
  }
}

// P5: ys[t][n].s += Sb[t/L][n] for t >= K'
__global__ __launch_bounds__(TPB) void p5_fixs(
    const unsigned int* __restrict__ hdr, const float* __restrict__ buf2,
    float* __restrict__ ys)
{
  unsigned int Kp = hdr[0];
  size_t e = (size_t)Kp * NN + (size_t)blockIdx.x * TPB + threadIdx.x;
  if (e >= (size_t)TT * NN) return;
  unsigned int t = (unsigned int)(e >> 12);        // /NN
  unsigned int n = (unsigned int)(e & (NN - 1));
  unsigned int g = t >> 6;                         // /LSEG
  ys[e * 3 + 2] += buf2[(size_t)g * NN + n];
}

extern "C" void kernel_launch(void* const* d_in, const int* in_sizes, int n_in,
                              void* d_out, int out_size, void* d_ws, size_t ws_size,
                              hipStream_t stream)
{
  (void)in_sizes; (void)n_in; (void)out_size; (void)ws_size;
  const float* ts  = (const float*)d_in[0];
  const float* inp = (const float*)d_in[1];
  const float* w   = (const float*)d_in[2];
  const float* v0  = (const float*)d_in[3];
  const float* i0  = (const float*)d_in[4];
  const float* mu  = (const float*)d_in[5];
  const float* s0u = (const float*)d_in[6];
  const float* ru  = (const float*)d_in[7];
  const int*   mx  = (const int*)d_in[8];
  float* ys = (float*)d_out;

  char* wsb = (char*)d_ws;
  unsigned int* hdr = (unsigned int*)wsb;                 // 64 B used
  float* buf1 = (float*)(wsb + 1024);                     // NSEG*NN*4 = 512 KB
  float* buf2 = buf1 + (size_t)NSEG * NN;                 // 512 KB

  // single-workgroup phase A: no slots, no memset, intra-CU barrier only
  phaseA<<<1, TPA, 0, stream>>>(ts, inp, w, v0, i0, mu, s0u, ru, mx, ys, hdr);
  p1_segc<<<NSEG * 16, TPB, 0, stream>>>(ts, inp, mu, ys, hdr, buf1);
  p2_scanv<<<NN / TPB, TPB, 0, stream>>>(ts, mu, ys, hdr, buf1);
  p3_seg<<<NSEG * 16, TPB, 0, stream>>>(ts, inp, mu, hdr, buf1, buf2, ys);
  p4_scans<<<NN / TPB, TPB, 0, stream>>>(ys, hdr, buf2);
  p5_fixs<<<(TT - 128) * NN / TPB, TPB, 0, stream>>>(hdr, buf2, ys);
}

// Round 2
// 647.117 us; speedup vs baseline: 1.2623x; 1.2623x over previous
//
#include <hip/hip_runtime.h>
#include <stddef.h>

#define TT 2048
#define NN 4096
#define LSEG 64
#define NSEG (TT / LSEG)   // 32
#define NBLK 16            // phase A blocks, ONE WAVE each
#define TPA 64             // phase A threads per block (= 1 wave, no __syncthreads)
#define NPT 4              // neurons per thread (NBLK*TPA*NPT == NN)
#define TPB 256
#define MAXU 0xFFFFFFFFu
#define NOFIRE 0xFFFFFFFEu

// ---------------- Phase A: exact coupled simulation, software-pipelined ----------------
// 16 blocks x 64 threads (1 wave), 4 neurons/thread, state in registers.
// Pipelined handshake (all bit-exact vs reference; only the SCHEDULE moves):
//   iter t: poll slots[t-1]  (published one full iteration ago -> usually landed)
//           issue gather w[gm(t-1)]           (consumed at iter t+1)
//           resolve i(t-1) with gather gm(t-2) (issued one full iteration ago)
//           drift step t-1 in reference op order; apply transition with ev(t-1)
//           store ys[t-2]   (2-deferred)
//           compute ev(t) from exact v(t),s(t); publish block-min to slots[t]
// One wave per block => reduce/broadcast is shfl-only: no barriers, no vmcnt(0) drains.
__global__ __launch_bounds__(TPA) void phaseA(
    const float* __restrict__ ts, const float* __restrict__ inp,
    const float* __restrict__ w, const float* __restrict__ v0,
    const float* __restrict__ i0, const float* __restrict__ mu,
    const float* __restrict__ s0u, const float* __restrict__ ru,
    const int* __restrict__ mx, float* __restrict__ ys,
    unsigned int* __restrict__ hdr, unsigned int* __restrict__ slots)
{
#pragma clang fp contract(off)
  const int tid = threadIdx.x;              // 0..63
  const int blk = blockIdx.x;               // 0..15
  const int idx4 = blk * TPA + tid;         // float4 index within a row (NN/4)
  const int n0 = idx4 * NPT;                // first neuron id of this thread
  const float dt = ts[1] - ts[0];
  const float mu1 = mu[0], mu2 = mu[1];
  const int maxs = mx[0];

  const float4* inp4 = (const float4*)inp;
  const float4* ru4  = (const float4*)ru;
  const float4* w4   = (const float4*)w;

  float4 a4;
  a4 = ((const float4*)v0)[idx4];  float v[NPT]    = {a4.x, a4.y, a4.z, a4.w};
  a4 = ((const float4*)i0)[idx4];  float i_nw[NPT] = {a4.x, a4.y, a4.z, a4.w};
  a4 = ((const float4*)s0u)[idx4];
  float s[NPT] = {logf(a4.x + 1e-12f) - 0.01f, logf(a4.y + 1e-12f) - 0.01f,
                  logf(a4.z + 1e-12f) - 0.01f, logf(a4.w + 1e-12f) - 0.01f};

  float snP[NPT] = {0.f, 0.f, 0.f, 0.f};    // s_n(t-1), saved for transition at iter t
  bool  evP[NPT] = {false, false, false, false};   // ev(t-1)
  bool  aw[NPT]  = {false, false, false, false};   // pending w-row add flags
  float wvP[NPT] = {0.f, 0.f, 0.f, 0.f};           // gather result for gm(t-2)
  float4 inp_prev = make_float4(0.f,0.f,0.f,0.f);  // inp row t-1
  float4 ru_prev  = make_float4(0.f,0.f,0.f,0.f);  // ru  row t-1
  int nsp = 0;
  int t_stop = TT;
  bool pubbed = false;

  for (int t = 0; t <= TT; ++t) {
    // ---- 1. poll gm(t-1): 64-lane coalesced load of the 64 B slot row + ballot
    unsigned int gm1 = NOFIRE;
    if (t >= 1 && pubbed) {
      const unsigned int* row = &slots[(size_t)(t - 1) * NBLK];
      unsigned int x = MAXU;
      long g = 0;
      for (;;) {
        x = __hip_atomic_load(&row[tid & (NBLK - 1)], __ATOMIC_RELAXED,
                              __HIP_MEMORY_SCOPE_AGENT);
        if (__ballot(x != MAXU) == ~0ULL) break;
        if (++g > (1L << 20)) break;       // safety escape (bug -> wrong, not hang)
      }
      gm1 = x;
#pragma unroll
      for (int off = 1; off < NBLK; off <<= 1) {   // min over the 16 slots
        unsigned int o = (unsigned int)__shfl_xor((int)gm1, off, 64);
        gm1 = gm1 < o ? gm1 : o;
      }
    }
    bool fire1 = (gm1 < (unsigned int)NN) && (nsp < maxs);   // fire(t-1)
    if (fire1) nsp += 1;                                     // nsp = nsp(t)

    // ---- 2. prefetch rows t (consumed next iteration)
    float4 inp_pref = make_float4(0.f,0.f,0.f,0.f);
    float4 ru_pref  = make_float4(0.f,0.f,0.f,0.f);
    if (t < TT) {
      inp_pref = inp4[(size_t)t * (NN / 4) + idx4];
      ru_pref  = ru4[(size_t)t * (NN / 4) + idx4];
    }
    // ---- 3. issue w-row gather for gm(t-1) (consumed next iteration)
    float4 wrN = make_float4(0.f,0.f,0.f,0.f);
    if (fire1) wrN = w4[(size_t)gm1 * (NN / 4) + idx4];

    if (t >= 1) {
      // ---- 4. resolve i(t-1): apply gm(t-2)'s w row (gathered a full iter ago)
      float ifull[NPT];
#pragma unroll
      for (int k = 0; k < NPT; ++k) ifull[k] = aw[k] ? (i_nw[k] + wvP[k]) : i_nw[k];
      // ---- 5. store ys[t-2] = y(t-1), now exact (2-deferred)
      if (t >= 2) {
        size_t o = ((size_t)(t - 2) * NN + (size_t)n0) * 3;
        float4* yo = (float4*)(ys + o);
        yo[0] = make_float4(v[0], ifull[0], s[0], v[1]);
        yo[1] = make_float4(ifull[1], s[1], v[2], ifull[2]);
        yo[2] = make_float4(s[2], v[3], ifull[3], s[3]);
      }
      // ---- 6. drift of step t-1 (reference op order, no contraction)
      float iv[NPT] = {inp_prev.x, inp_prev.y, inp_prev.z, inp_prev.w};
      float rv[NPT] = {ru_prev.x,  ru_prev.y,  ru_prev.z,  ru_prev.w};
      float vn[NPT], in_[NPT];
#pragma unroll
      for (int k = 0; k < NPT; ++k) {
        vn[k]  = v[k] + dt * (mu1 * (ifull[k] - v[k]) + mu1 * iv[k]);
        in_[k] = ifull[k] + dt * (-mu2 * ifull[k]);
      }
      // ---- 7. transition of step t-1 using ev(t-1) and fire(t-1)
      if (fire1) {
#pragma unroll
        for (int k = 0; k < NPT; ++k) {
          if (evP[k]) {
            v[k] = vn[k] - 1.0f;
            s[k] = logf(rv[k] + 1e-12f) - 0.01f;   // logf only under rare ev path
            aw[k] = false;
          } else {
            v[k] = vn[k]; s[k] = snP[k]; aw[k] = true;   // w add pending (wrN)
          }
        }
      } else {
#pragma unroll
        for (int k = 0; k < NPT; ++k) { v[k] = vn[k]; s[k] = snP[k]; aw[k] = false; }
      }
#pragma unroll
      for (int k = 0; k < NPT; ++k) i_nw[k] = in_[k];
      wvP[0] = wrN.x; wvP[1] = wrN.y; wvP[2] = wrN.z; wvP[3] = wrN.w;
      // ---- 8. termination: first L-boundary with nsp(t) >= maxs (or end of horizon)
      if (t == TT || (nsp >= maxs && (t & (LSEG - 1)) == 0)) { t_stop = t; break; }
    }

    // ---- 9. events of step t from exact v(t),s(t); publish block-min
    {
      unsigned int m = NOFIRE;
#pragma unroll
      for (int k = 0; k < NPT; ++k) {
        float sig = 1.0f / (1.0f + expf(-v[k]));
        float sn = s[k] + dt * sig;
        bool e = sn >= 0.0f;
        snP[k] = sn; evP[k] = e;
        unsigned int c = e ? (unsigned int)(n0 + k) : NOFIRE;
        m = m < c ? m : c;
      }
      if (nsp < maxs) {
#pragma unroll
        for (int off = 1; off < 64; off <<= 1) {
          unsigned int o = (unsigned int)__shfl_xor((int)m, off, 64);
          m = m < o ? m : o;
        }
        if (tid == 0)
          __hip_atomic_store(&slots[(size_t)t * NBLK + blk], m,
                             __ATOMIC_RELAXED, __HIP_MEMORY_SCOPE_AGENT);
        pubbed = true;
      } else {
        pubbed = false;   // decoupled drift until the next L boundary
      }
    }
    inp_prev = inp_pref; ru_prev = ru_pref;
  }

  // ---- drain: store ys[t_stop-1] = y(t_stop) (resolve the last pending w add)
  {
    float ifull[NPT];
#pragma unroll
    for (int k = 0; k < NPT; ++k) ifull[k] = aw[k] ? (i_nw[k] + wvP[k]) : i_nw[k];
    size_t o = ((size_t)(t_stop - 1) * NN + (size_t)n0) * 3;
    float4* yo = (float4*)(ys + o);
    yo[0] = make_float4(v[0], ifull[0], s[0], v[1]);
    yo[1] = make_float4(ifull[1], s[1], v[2], ifull[2]);
    yo[2] = make_float4(s[2], v[3], ifull[3], s[3]);
  }
  if (blk == 0 && tid == 0) hdr[0] = (unsigned int)t_stop;
}

// ---------------- Phase B: decoupled closed-form tail (unchanged) ----------------
// P1: per (neuron, segment): C = sum_j a^(L-1-j) * b * (i_j + inp_j), i_j geometric.
__global__ __launch_bounds__(TPB) void p1_segc(
    const float* __restrict__ ts, const float* __restrict__ inp,
    const float* __restrict__ mu, const float* __restrict__ ys,
    const unsigned int* __restrict__ hdr, float* __restrict__ buf1)
{
  unsigned int Kp = hdr[0];
  unsigned int g0 = Kp / LSEG;
  unsigned int g = blockIdx.x >> 4;
  if (g < g0) return;
  int n = (blockIdx.x & 15) * TPB + threadIdx.x;
  float dt = ts[1] - ts[0];
  float mu1 = mu[0], mu2 = mu[1];
  float a = 1.0f - dt * mu1, b = dt * mu1, r = 1.0f - dt * mu2;
  float ibase = ys[((size_t)(Kp - 1) * NN + n) * 3 + 1];
  float ij = ibase * powf(r, (float)((int)(g * LSEG) - (int)Kp));
  float c = 0.0f;
  size_t base = (size_t)(g * LSEG) * NN + n;
  for (int j = 0; j < LSEG; ++j) {
    float x = inp[base + (size_t)j * NN];
    c = a * c + b * (ij + x);
    ij *= r;
  }
  buf1[(size_t)g * NN + n] = c;
}

// P2: per neuron, scan segment-boundary v:  v_{g+1} = a^L v_g + C_g (in place -> Vb)
__global__ __launch_bounds__(TPB) void p2_scanv(
    const float* __restrict__ ts, const float* __restrict__ mu,
    const float* __restrict__ ys, const unsigned int* __restrict__ hdr,
    float* __restrict__ buf1)
{
  unsigned int Kp = hdr[0];
  unsigned int g0 = Kp / LSEG;
  if (g0 >= NSEG) return;
  int n = blockIdx.x * TPB + threadIdx.x;
  float dt = ts[1] - ts[0];
  float mu1 = mu[0];
  float a = 1.0f - dt * mu1;
  float aL = a;
  for (int k = 0; k < 6; ++k) aL *= aL;   // a^64
  float v = ys[((size_t)(Kp - 1) * NN + n) * 3 + 0];
  for (unsigned int g = g0; g < NSEG; ++g) {
    float cg = buf1[(size_t)g * NN + n];
    buf1[(size_t)g * NN + n] = v;
    v = aL * v + cg;
  }
}

// P3: per (neuron, segment): replay 64 steps; write v,i and local s-prefix to ys;
// stash segment sigma-sum into buf2.
__global__ __launch_bounds__(TPB) void p3_seg(
    const float* __restrict__ ts, const float* __restrict__ inp,
    const float* __restrict__ mu, const unsigned int* __restrict__ hdr,
    const float* __restrict__ buf1, float* __restrict__ buf2,
    float* __restrict__ ys)
{
  unsigned int Kp = hdr[0];
  unsigned int g0 = Kp / LSEG;
  unsigned int g = blockIdx.x >> 4;
  if (g < g0) return;
  int n = (blockIdx.x & 15) * TPB + threadIdx.x;
  float dt = ts[1] - ts[0];
  float mu1 = mu[0], mu2 = mu[1];
  float r = 1.0f - dt * mu2;
  float v = buf1[(size_t)g * NN + n];
  float ibase = ys[((size_t)(Kp - 1) * NN + n) * 3 + 1];
  float i = ibase * powf(r, (float)((int)(g * LSEG) - (int)Kp));
  float sl = 0.0f;
  for (int j = 0; j < LSEG; ++j) {
    size_t t = (size_t)g * LSEG + j;
    float x = inp[t * NN + n];
    float sig = 1.0f / (1.0f + expf(-v));
    sl = sl + dt * sig;
    float vn  = v + dt * (mu1 * (i - v) + mu1 * x);
    float in_ = i + dt * (-mu2 * i);
    size_t o = (t * NN + n) * 3;
    ys[o] = vn; ys[o + 1] = in_; ys[o + 2] = sl;
    v = vn; i = in_;
  }
  buf2[(size_t)g * NN + n] = sl;
}

// P4: per neuron, scan sigma-sums -> s at segment starts (in place -> Sb)
__global__ __launch_bounds__(TPB) void p4_scans(
    const float* __restrict__ ys, const unsigned int* __restrict__ hdr,
    float* __restrict__ buf2)
{
  unsigned int Kp = hdr[0];
  unsigned int g0 = Kp / LSEG;
  if (g0 >= NSEG) return;
  int n = blockIdx.x * TPB + threadIdx.x;
  float s = ys[((size_t)(Kp - 1) * NN + n) * 3 + 2];
  for (unsigned int g = g0; g < NSEG; ++g) {
    float t = buf2[(size_t)g * NN + n];
    buf2[(size_t)g * NN + n] = s;
    s += t;
  }
}

// P5: ys[t][n].s += Sb[t/L][n] for t >= K'
__global__ __launch_bounds__(TPB) void p5_fixs(
    const unsigned int* __restrict__ hdr, const float* __restrict__ buf2,
    float* __restrict__ ys)
{
  unsigned int Kp = hdr[0];
  size_t e = (size_t)Kp * NN + (size_t)blockIdx.x * TPB + threadIdx.x;
  if (e >= (size_t)TT * NN) return;
  unsigned int t = (unsigned int)(e >> 12);        // /NN
  unsigned int n = (unsigned int)(e & (NN - 1));
  unsigned int g = t >> 6;                         // /LSEG
  ys[e * 3 + 2] += buf2[(size_t)g * NN + n];
}

extern "C" void kernel_launch(void* const* d_in, const int* in_sizes, int n_in,
                              void* d_out, int out_size, void* d_ws, size_t ws_size,
                              hipStream_t stream)
{
  (void)in_sizes; (void)n_in; (void)out_size; (void)ws_size;
  const float* ts  = (const float*)d_in[0];
  const float* inp = (const float*)d_in[1];
  const float* w   = (const float*)d_in[2];
  const float* v0  = (const float*)d_in[3];
  const float* i0  = (const float*)d_in[4];
  const float* mu  = (const float*)d_in[5];
  const float* s0u = (const float*)d_in[6];
  const float* ru  = (const float*)d_in[7];
  const int*   mx  = (const int*)d_in[8];
  float* ys = (float*)d_out;

  char* wsb = (char*)d_ws;
  unsigned int* hdr   = (unsigned int*)wsb;                       // 64 B used
  unsigned int* slots = (unsigned int*)(wsb + 1024);              // T*16*4 = 128 KB
  float* buf1 = (float*)(wsb + 1024 + (size_t)TT * NBLK * 4);     // 512 KB
  float* buf2 = buf1 + (size_t)NSEG * NN;                         // 512 KB

  // barrier slots must start as 0xFFFFFFFF (= "not arrived")
  hipMemsetAsync(slots, 0xFF, (size_t)TT * NBLK * 4, stream);

  phaseA<<<NBLK, TPA, 0, stream>>>(ts, inp, w, v0, i0, mu, s0u, ru, mx, ys, hdr, slots);
  p1_segc<<<NSEG * 16, TPB, 0, stream>>>(ts, inp, mu, ys, hdr, buf1);
  p2_scanv<<<NN / TPB, TPB, 0, stream>>>(ts, mu, ys, hdr, buf1);
  p3_seg<<<NSEG * 16, TPB, 0, stream>>>(ts, inp, mu, hdr, buf1, buf2, ys);
  p4_scans<<<NN / TPB, TPB, 0, stream>>>(ys, hdr, buf2);
  p5_fixs<<<(TT - 128) * NN / TPB, TPB, 0, stream>>>(hdr, buf2, ys);
}